// Round 19
// baseline (213.065 us; speedup 1.0000x reference)
//
#include <hip/hip_runtime.h>
#include <hip/hip_bf16.h>

typedef __bf16 bf16x8 __attribute__((ext_vector_type(8)));
typedef float f32x4 __attribute__((ext_vector_type(4)));
typedef float f32x16 __attribute__((ext_vector_type(16)));
typedef short s16x4 __attribute__((ext_vector_type(4)));
typedef short s16x8 __attribute__((ext_vector_type(8)));

__device__ __forceinline__ short f2bf(float f) {
  union { __bf16 h; short s; } p; p.h = (__bf16)f; return p.s;
}
__device__ __forceinline__ float bf2f(short s) {
  union { unsigned u; float f; } v; v.u = ((unsigned)(unsigned short)s) << 16;
  return v.f;
}
__device__ __forceinline__ void gload16(const void* g, void* l) {
  __builtin_amdgcn_global_load_lds(
      (const __attribute__((address_space(1))) unsigned*)g,
      (__attribute__((address_space(3))) unsigned*)l, 16, 0, 0);
}
__device__ __forceinline__ unsigned pack2(float lo, float hi) {
  union { __bf16 h[2]; unsigned u; } p;
  p.h[0] = (__bf16)lo; p.h[1] = (__bf16)hi;   // v_cvt_pk_bf16_f32
  return p.u;
}
__device__ __forceinline__ float vsum16(const f32x16& v) {
  const float a0 = v[0] + v[1], a1 = v[2] + v[3], a2 = v[4] + v[5], a3 = v[6] + v[7];
  const float a4 = v[8] + v[9], a5 = v[10] + v[11], a6 = v[12] + v[13], a7 = v[14] + v[15];
  return ((a0 + a1) + (a2 + a3)) + ((a4 + a5) + (a6 + a7));
}

constexpr float KSC = 0.18033688f;  // 1/sqrt(64) * log2(e) — folded into Q-rope in attn

// ---------------- fused prep: x fp32->bf16 (z=4) + 4 weight transposes (z=0..3) ----------------
__global__ __launch_bounds__(256) void prep_kernel(const float* __restrict__ x,
                                                   const float* __restrict__ wq,
                                                   const float* __restrict__ wk,
                                                   const float* __restrict__ wv,
                                                   const float* __restrict__ wo,
                                                   short* __restrict__ xb,
                                                   short* __restrict__ wqT,
                                                   short* __restrict__ wkT,
                                                   short* __restrict__ wvT,
                                                   short* __restrict__ woT) {
  __shared__ float T[32][36];
  const int z = blockIdx.z;
  if (z == 4) {
    const int bid = blockIdx.y * 64 + blockIdx.x;
    const int i0 = bid * 512 + threadIdx.x;
    #pragma unroll
    for (int q = 0; q < 2; ++q) {
      const int i = i0 + q * 256;
      const float4 v = reinterpret_cast<const float4*>(x)[i];
      s16x4 o;
      o[0] = f2bf(v.x); o[1] = f2bf(v.y); o[2] = f2bf(v.z); o[3] = f2bf(v.w);
      reinterpret_cast<s16x4*>(xb)[i] = o;
    }
    return;
  }
  const float* W; short* WT; int N;
  if (z == 0)      { W = wq; WT = wqT; N = 2048; }
  else if (z == 1) { W = wk; WT = wkT; N = 512; }
  else if (z == 2) { W = wv; WT = wvT; N = 512; }
  else             { W = wo; WT = woT; N = 2048; }
  const int k0 = blockIdx.x * 32, n0 = blockIdx.y * 32;
  if (n0 >= N) return;
  const int r = threadIdx.x >> 3;
  const int c4 = (threadIdx.x & 7) * 4;
  {
    const float4 v = *reinterpret_cast<const float4*>(&W[(size_t)(k0 + r) * N + n0 + c4]);
    T[r][c4 + 0] = v.x; T[r][c4 + 1] = v.y; T[r][c4 + 2] = v.z; T[r][c4 + 3] = v.w;
  }
  __syncthreads();
  {
    s16x4 o;
    #pragma unroll
    for (int i = 0; i < 4; ++i) o[i] = f2bf(T[c4 + i][r]);
    *reinterpret_cast<s16x4*>(&WT[(size_t)(n0 + r) * 2048 + k0 + c4]) = o;
  }
}

// ---------------- RoPE on K only (Q-rope fused into attn) ----------------
__global__ void rope_k(short* __restrict__ K, const float* __restrict__ cosT,
                       const float* __restrict__ sinT) {
  const int i = blockIdx.x * blockDim.x + threadIdx.x;
  const int s = (i >> 6) & 2047;
  const int p0 = (i & 7) * 4;
  s16x8 v = *reinterpret_cast<const s16x8*>(&K[(size_t)i * 8]);
  #pragma unroll
  for (int jj = 0; jj < 4; ++jj) {
    const float c = cosT[s * 32 + p0 + jj];
    const float sn = sinT[s * 32 + p0 + jj];
    const float e = bf2f(v[2 * jj]), o = bf2f(v[2 * jj + 1]);
    v[2 * jj] = f2bf(e * c - o * sn);
    v[2 * jj + 1] = f2bf(e * sn + o * c);
  }
  *reinterpret_cast<s16x8*>(&K[(size_t)i * 8]) = v;
}

// ---------------- QKV GEMM (R16-verified, verbatim): 256x192, grid 16x16 ----------------
__global__ __launch_bounds__(512, 2) void gemm_qkv(const short* __restrict__ A,
                                                   const short* __restrict__ BT,
                                                   short* __restrict__ C0,   // Q [4096][2048]
                                                   short* __restrict__ C1,   // K [4096][512]
                                                   short* __restrict__ C2) { // VT [16][64][2048]
  constexpr int BM = 256, BN = 192, BK = 64, K = 2048, NT = K / BK;
  __shared__ short As[2][BM * BK];
  __shared__ short Bs[2][BN * BK];
  const int tid = threadIdx.x, lane = tid & 63, wid = tid >> 6;
  const int wm = wid >> 1, wn = wid & 1;
  const int lr = lane & 15, hi2 = lane >> 4;

  int bid = blockIdx.y * 16 + blockIdx.x;
  bid = (bid & 7) * 32 + (bid >> 3);
  const int row0 = (bid & 15) * BM;
  const int col0 = (bid >> 4) * BN;

  size_t aSrc[4]; int aDst[4];
  size_t bSrc[3]; int bDst[3];
  #pragma unroll
  for (int i = 0; i < 4; ++i) {
    const int c = i * 512 + tid, r = c >> 3, ch = c & 7;
    aSrc[i] = (size_t)(row0 + r) * K + (ch ^ (r & 7)) * 8;
    aDst[i] = c * 8;
  }
  #pragma unroll
  for (int i = 0; i < 3; ++i) {
    const int c = i * 512 + tid, r = c >> 3, ch = c & 7;
    bSrc[i] = (size_t)(col0 + r) * K + (ch ^ (r & 7)) * 8;
    bDst[i] = c * 8;
  }

  f32x4 acc[4][6] = {};

  #pragma unroll
  for (int i = 0; i < 4; ++i) gload16(&A[aSrc[i]], &As[0][aDst[i]]);
  #pragma unroll
  for (int i = 0; i < 3; ++i) gload16(&BT[bSrc[i]], &Bs[0][bDst[i]]);

  int buf = 0;
  for (int t = 0; t < NT; ++t) {
    __syncthreads();
    if (t + 1 < NT) {
      const int k1 = (t + 1) * BK;
      #pragma unroll
      for (int i = 0; i < 4; ++i) gload16(&A[aSrc[i] + k1], &As[buf ^ 1][aDst[i]]);
      #pragma unroll
      for (int i = 0; i < 3; ++i) gload16(&BT[bSrc[i] + k1], &Bs[buf ^ 1][bDst[i]]);
    }
    #pragma unroll
    for (int ks = 0; ks < 2; ++ks) {
      const int sw = ((ks * 4 + hi2) ^ (lr & 7)) * 8;
      bf16x8 af[4], bfr[6];
      #pragma unroll
      for (int m = 0; m < 4; ++m)
        af[m] = *reinterpret_cast<const bf16x8*>(
            &As[buf][(wm * 64 + m * 16 + lr) * BK + sw]);
      #pragma unroll
      for (int n = 0; n < 6; ++n)
        bfr[n] = *reinterpret_cast<const bf16x8*>(
            &Bs[buf][(wn * 96 + n * 16 + lr) * BK + sw]);
      __builtin_amdgcn_s_setprio(1);
      #pragma unroll
      for (int m = 0; m < 4; ++m)
        #pragma unroll
        for (int n = 0; n < 6; ++n)
          acc[m][n] = __builtin_amdgcn_mfma_f32_16x16x32_bf16(af[m], bfr[n], acc[m][n], 0, 0, 0);
      __builtin_amdgcn_s_setprio(0);
    }
    buf ^= 1;
  }

  const int lc = lane & 15, lr4 = (lane >> 4) * 4;
  #pragma unroll
  for (int m = 0; m < 4; ++m) {
    #pragma unroll
    for (int n = 0; n < 6; ++n) {
      const int row = row0 + wm * 64 + m * 16 + lr4;
      const int col = col0 + wn * 96 + n * 16 + lc;
      if (col < 2048) {
        #pragma unroll
        for (int i = 0; i < 4; ++i)
          C0[(size_t)(row + i) * 2048 + col] = f2bf(acc[m][n][i]);
      } else if (col < 2560) {
        #pragma unroll
        for (int i = 0; i < 4; ++i)
          C1[(size_t)(row + i) * 512 + (col - 2048)] = f2bf(acc[m][n][i]);
      } else {
        const int c2 = col - 2560;
        const int kvh = c2 >> 6, d = c2 & 63;
        const int bb = row >> 11, st = row & 2047;
        s16x4 o4;
        #pragma unroll
        for (int i = 0; i < 4; ++i) o4[i] = f2bf(acc[m][n][i]);
        *reinterpret_cast<s16x4*>(&C2[((size_t)(bb * 8 + kvh) * 64 + d) * 2048 + st]) = o4;
      }
    }
  }
}

// ---------------- out-projection GEMM (R17-verified 128x256 structure; nt C-stores) ----------------
__global__ __launch_bounds__(512, 2) void gemm_out(const short* __restrict__ A,
                                                   const short* __restrict__ BT,
                                                   float* __restrict__ C,
                                                   int M, int N, int K) {
  constexpr int BM = 128, BN = 256, BK = 64;
  __shared__ short As[2][BM * BK];
  __shared__ short Bs[2][BN * BK];
  const int tid = threadIdx.x, lane = tid & 63, wid = tid >> 6;
  const int wm = wid >> 2, wn = wid & 3;
  const int lr = lane & 15, hi2 = lane >> 4;

  const int nwg = gridDim.x * gridDim.y;
  int bid = blockIdx.y * gridDim.x + blockIdx.x;
  bid = (bid & 7) * (nwg >> 3) + (bid >> 3);
  const int row0 = (bid % gridDim.x) * BM;
  const int col0 = (bid / gridDim.x) * BN;

  size_t aSrc[2]; int aDst[2];
  size_t bSrc[4]; int bDst[4];
  #pragma unroll
  for (int i = 0; i < 2; ++i) {
    const int c = i * 512 + tid, r = c >> 3, ch = c & 7;
    aSrc[i] = (size_t)(row0 + r) * K + (ch ^ (r & 7)) * 8;
    aDst[i] = c * 8;
  }
  #pragma unroll
  for (int i = 0; i < 4; ++i) {
    const int c = i * 512 + tid, r = c >> 3, ch = c & 7;
    bSrc[i] = (size_t)(col0 + r) * K + (ch ^ (r & 7)) * 8;
    bDst[i] = c * 8;
  }

  f32x4 acc[4][4] = {};
  const int NT = K / BK;

  #pragma unroll
  for (int i = 0; i < 2; ++i) gload16(&A[aSrc[i]], &As[0][aDst[i]]);
  #pragma unroll
  for (int i = 0; i < 4; ++i) gload16(&BT[bSrc[i]], &Bs[0][bDst[i]]);

  int buf = 0;
  for (int t = 0; t < NT; ++t) {
    __syncthreads();
    if (t + 1 < NT) {
      const int k1 = (t + 1) * BK;
      #pragma unroll
      for (int i = 0; i < 2; ++i) gload16(&A[aSrc[i] + k1], &As[buf ^ 1][aDst[i]]);
      #pragma unroll
      for (int i = 0; i < 4; ++i) gload16(&BT[bSrc[i] + k1], &Bs[buf ^ 1][bDst[i]]);
    }
    #pragma unroll
    for (int ks = 0; ks < 2; ++ks) {
      const int sw = ((ks * 4 + hi2) ^ (lr & 7)) * 8;
      bf16x8 af[4], bfr[4];
      #pragma unroll
      for (int m = 0; m < 4; ++m)
        af[m] = *reinterpret_cast<const bf16x8*>(&As[buf][(wm * 64 + m * 16 + lr) * BK + sw]);
      #pragma unroll
      for (int n = 0; n < 4; ++n)
        bfr[n] = *reinterpret_cast<const bf16x8*>(&Bs[buf][(wn * 64 + n * 16 + lr) * BK + sw]);
      __builtin_amdgcn_s_setprio(1);
      #pragma unroll
      for (int m = 0; m < 4; ++m)
        #pragma unroll
        for (int n = 0; n < 4; ++n)
          acc[m][n] = __builtin_amdgcn_mfma_f32_16x16x32_bf16(af[m], bfr[n], acc[m][n], 0, 0, 0);
      __builtin_amdgcn_s_setprio(0);
    }
    buf ^= 1;
  }

  const int lc = lane & 15, lr4 = (lane >> 4) * 4;
  #pragma unroll
  for (int m = 0; m < 4; ++m)
    #pragma unroll
    for (int n = 0; n < 4; ++n)
      #pragma unroll
      for (int i = 0; i < 4; ++i) {
        const int row = row0 + wm * 64 + m * 16 + lr4 + i;
        const int col = col0 + wn * 64 + n * 16 + lc;
        __builtin_nontemporal_store(acc[m][n][i], &C[(size_t)row * N + col]);
      }
}

// ---------------- causal GQA flash attention (R17-verified, verbatim) ----------------
__device__ __forceinline__ void rope_qfrag(bf16x8 qf[4], const float* __restrict__ cosT,
                                           const float* __restrict__ sinT, int qrow, int hi) {
  #pragma unroll
  for (int ds = 0; ds < 4; ++ds) {
    const int p0 = ds * 8 + hi * 4;
    const float4 cv = *reinterpret_cast<const float4*>(&cosT[qrow * 32 + p0]);
    const float4 sv = *reinterpret_cast<const float4*>(&sinT[qrow * 32 + p0]);
    const float ca[4] = {cv.x, cv.y, cv.z, cv.w};
    const float sa[4] = {sv.x, sv.y, sv.z, sv.w};
    union { bf16x8 v; s16x8 s; } u; u.v = qf[ds];
    s16x8 r;
    #pragma unroll
    for (int jj = 0; jj < 4; ++jj) {
      const float c = ca[jj] * KSC;
      const float sn = sa[jj] * KSC;
      const float e = bf2f(u.s[2 * jj]), o = bf2f(u.s[2 * jj + 1]);
      r[2 * jj] = f2bf(e * c - o * sn);
      r[2 * jj + 1] = f2bf(e * sn + o * c);
    }
    union { s16x8 s; bf16x8 v; } w; w.s = r;
    qf[ds] = w.v;
  }
}

template <bool MASKED>
__device__ __forceinline__ void ptile(const short* __restrict__ Ksb,
                                      const short* __restrict__ Vsb,
                                      const bf16x8 qf[4], int kb, int qrow,
                                      int l31, int hi,
                                      f32x16& o0, f32x16& o1, float& l_r) {
  f32x16 sa0 = {}, sa1 = {};
  __builtin_amdgcn_s_setprio(1);
  #pragma unroll
  for (int ds = 0; ds < 4; ++ds) {
    const int c0 = ((ds * 2 + hi) ^ (l31 & 7)) * 8;
    const bf16x8 kf0 = *reinterpret_cast<const bf16x8*>(&Ksb[l31 * 64 + c0]);
    const bf16x8 kf1 = *reinterpret_cast<const bf16x8*>(&Ksb[(32 + l31) * 64 + c0]);
    sa0 = __builtin_amdgcn_mfma_f32_32x32x16_bf16(kf0, qf[ds], sa0, 0, 0, 0);
    sa1 = __builtin_amdgcn_mfma_f32_32x32x16_bf16(kf1, qf[ds], sa1, 0, 0, 0);
  }
  __builtin_amdgcn_s_setprio(0);
  if (MASKED) {
    #pragma unroll
    for (int r = 0; r < 16; ++r) {
      const int kk = kb + (r & 3) + 8 * (r >> 2) + 4 * hi;
      if (kk > qrow) sa0[r] = -1e30f;
      if (kk + 32 > qrow) sa1[r] = -1e30f;
    }
  }
  #pragma unroll
  for (int r = 0; r < 16; ++r) {
    sa0[r] = exp2f(sa0[r]);
    sa1[r] = exp2f(sa1[r]);
  }
  l_r += vsum16(sa0) + vsum16(sa1);
  bf16x8 paf[4];
  #pragma unroll
  for (int ks = 0; ks < 4; ++ks) {
    union { unsigned w[4]; bf16x8 v; } u;
    #pragma unroll
    for (int w2 = 0; w2 < 4; ++w2) {
      const int rbase = (ks & 1) * 8 + w2 * 2;
      if (ks < 2) u.w[w2] = pack2(sa0[rbase], sa0[rbase + 1]);
      else        u.w[w2] = pack2(sa1[rbase], sa1[rbase + 1]);
    }
    paf[ks] = u.v;
  }
  __builtin_amdgcn_s_setprio(1);
  #pragma unroll
  for (int ks = 0; ks < 4; ++ks) {
    const int g0 = ((2 * ks) ^ (l31 & 7)) * 8 + hi * 4;
    const int g1 = ((2 * ks + 1) ^ (l31 & 7)) * 8 + hi * 4;
    union { s16x4 h2[2]; bf16x8 v; } a0, a1;
    a0.h2[0] = *reinterpret_cast<const s16x4*>(&Vsb[l31 * 64 + g0]);
    a0.h2[1] = *reinterpret_cast<const s16x4*>(&Vsb[l31 * 64 + g1]);
    a1.h2[0] = *reinterpret_cast<const s16x4*>(&Vsb[(32 + l31) * 64 + g0]);
    a1.h2[1] = *reinterpret_cast<const s16x4*>(&Vsb[(32 + l31) * 64 + g1]);
    o0 = __builtin_amdgcn_mfma_f32_32x32x16_bf16(a0.v, paf[ks], o0, 0, 0, 0);
    o1 = __builtin_amdgcn_mfma_f32_32x32x16_bf16(a1.v, paf[ks], o1, 0, 0, 0);
  }
  __builtin_amdgcn_s_setprio(0);
}

template <bool MA>
__device__ __forceinline__ void ptile2(const short* __restrict__ Ksb,
                                       const short* __restrict__ Vsb,
                                       const bf16x8 qfA[4], const bf16x8 qfB[4],
                                       int kb, int qrowA, int l31, int hi,
                                       f32x16& oA0, f32x16& oA1, f32x16& oB0, f32x16& oB1,
                                       float& lA, float& lB) {
  f32x16 a0 = {}, a1 = {}, b0 = {}, b1 = {};
  __builtin_amdgcn_s_setprio(1);
  #pragma unroll
  for (int ds = 0; ds < 4; ++ds) {
    const int c0 = ((ds * 2 + hi) ^ (l31 & 7)) * 8;
    const bf16x8 kf0 = *reinterpret_cast<const bf16x8*>(&Ksb[l31 * 64 + c0]);
    const bf16x8 kf1 = *reinterpret_cast<const bf16x8*>(&Ksb[(32 + l31) * 64 + c0]);
    a0 = __builtin_amdgcn_mfma_f32_32x32x16_bf16(kf0, qfA[ds], a0, 0, 0, 0);
    b0 = __builtin_amdgcn_mfma_f32_32x32x16_bf16(kf0, qfB[ds], b0, 0, 0, 0);
    a1 = __builtin_amdgcn_mfma_f32_32x32x16_bf16(kf1, qfA[ds], a1, 0, 0, 0);
    b1 = __builtin_amdgcn_mfma_f32_32x32x16_bf16(kf1, qfB[ds], b1, 0, 0, 0);
  }
  __builtin_amdgcn_s_setprio(0);
  if (MA) {
    #pragma unroll
    for (int r = 0; r < 16; ++r) {
      const int kk = kb + (r & 3) + 8 * (r >> 2) + 4 * hi;
      if (kk > qrowA) a0[r] = -1e30f;
      if (kk + 32 > qrowA) a1[r] = -1e30f;
    }
  }
  #pragma unroll
  for (int r = 0; r < 16; ++r) {
    a0[r] = exp2f(a0[r]);
    b0[r] = exp2f(b0[r]);
    a1[r] = exp2f(a1[r]);
    b1[r] = exp2f(b1[r]);
  }
  lA += vsum16(a0) + vsum16(a1);
  lB += vsum16(b0) + vsum16(b1);
  bf16x8 pafA[4], pafB[4];
  #pragma unroll
  for (int ks = 0; ks < 4; ++ks) {
    union { unsigned w[4]; bf16x8 v; } ua, ub;
    #pragma unroll
    for (int w2 = 0; w2 < 4; ++w2) {
      const int rbase = (ks & 1) * 8 + w2 * 2;
      if (ks < 2) { ua.w[w2] = pack2(a0[rbase], a0[rbase + 1]);
                    ub.w[w2] = pack2(b0[rbase], b0[rbase + 1]); }
      else        { ua.w[w2] = pack2(a1[rbase], a1[rbase + 1]);
                    ub.w[w2] = pack2(b1[rbase], b1[rbase + 1]); }
    }
    pafA[ks] = ua.v; pafB[ks] = ub.v;
  }
  __builtin_amdgcn_s_setprio(1);
  #pragma unroll
  for (int ks = 0; ks < 4; ++ks) {
    const int g0 = ((2 * ks) ^ (l31 & 7)) * 8 + hi * 4;
    const int g1 = ((2 * ks + 1) ^ (l31 & 7)) * 8 + hi * 4;
    union { s16x4 h2[2]; bf16x8 v; } v0, v1;
    v0.h2[0] = *reinterpret_cast<const s16x4*>(&Vsb[l31 * 64 + g0]);
    v0.h2[1] = *reinterpret_cast<const s16x4*>(&Vsb[l31 * 64 + g1]);
    v1.h2[0] = *reinterpret_cast<const s16x4*>(&Vsb[(32 + l31) * 64 + g0]);
    v1.h2[1] = *reinterpret_cast<const s16x4*>(&Vsb[(32 + l31) * 64 + g1]);
    oA0 = __builtin_amdgcn_mfma_f32_32x32x16_bf16(v0.v, pafA[ks], oA0, 0, 0, 0);
    oB0 = __builtin_amdgcn_mfma_f32_32x32x16_bf16(v0.v, pafB[ks], oB0, 0, 0, 0);
    oA1 = __builtin_amdgcn_mfma_f32_32x32x16_bf16(v1.v, pafA[ks], oA1, 0, 0, 0);
    oB1 = __builtin_amdgcn_mfma_f32_32x32x16_bf16(v1.v, pafB[ks], oB1, 0, 0, 0);
  }
  __builtin_amdgcn_s_setprio(0);
}

__global__ __launch_bounds__(512, 2) void attn3(const short* __restrict__ Q,
                                                const short* __restrict__ K,
                                                const short* __restrict__ VT,
                                                const float* __restrict__ cosT,
                                                const float* __restrict__ sinT,
                                                short* __restrict__ O) {
  constexpr int S = 2048, H = 32;
  const int pair = blockIdx.x, kvh = blockIdx.y, b = blockIdx.z;
  const int tid = threadIdx.x, lane = tid & 63, wid = tid >> 6;
  const int hg = wid & 3, rowhalf = wid >> 2;
  const int h = kvh * 4 + hg;
  const int l31 = lane & 31, hi = lane >> 5;
  const int qpA = pair, qpB = 31 - pair;
  const int q0A = qpA * 64 + rowhalf * 32, q0B = qpB * 64 + rowhalf * 32;
  const int qrowA = q0A + l31, qrowB = q0B + l31;
  const int bk = b * 8 + kvh;

  __shared__ short Ks[2][16384];
  __shared__ short Vs[2][16384];

  bf16x8 qfA[4], qfB[4];
  {
    const size_t qa = ((size_t)(b * S + qrowA) * H + h) * 64;
    const size_t qb = ((size_t)(b * S + qrowB) * H + h) * 64;
    #pragma unroll
    for (int ds = 0; ds < 4; ++ds) {
      qfA[ds] = *reinterpret_cast<const bf16x8*>(&Q[qa + ds * 16 + hi * 8]);
      qfB[ds] = *reinterpret_cast<const bf16x8*>(&Q[qb + ds * 16 + hi * 8]);
    }
    rope_qfrag(qfA, cosT, sinT, qrowA, hi);
    rope_qfrag(qfB, cosT, sinT, qrowB, hi);
  }

  f32x16 oA0 = {}, oA1 = {}, oB0 = {}, oB1 = {};
  float lA = 0.f, lB = 0.f;

  const int njt = (qpB + 4) >> 2;
  const size_t kroot = ((size_t)b * S * 8 + kvh) * 64;
  const size_t vroot = (size_t)bk * 64 * S;

  const int sr = tid >> 3, sch = tid & 7;
  const int cs8 = (sch ^ (sr & 7)) * 8;

  auto stage = [&](int j, int bufi) {
    #pragma unroll
    for (int s = 0; s < 4; ++s) {
      gload16(&K[kroot + (size_t)(j * 256 + s * 64 + sr) * 512 + cs8],
              &Ks[bufi][s * 4096 + tid * 8]);
      gload16(&VT[vroot + (size_t)sr * S + j * 256 + s * 64 + cs8],
              &Vs[bufi][s * 4096 + tid * 8]);
    }
  };

  stage(0, 0);
  __syncthreads();

  int cur = 0;
  for (int j = 0; j < njt; ++j) {
    if (j + 1 < njt) stage(j + 1, cur ^ 1);
    #pragma unroll
    for (int s = 0; s < 4; ++s) {
      const int kb = j * 256 + s * 64;
      const short* Ksb = &Ks[cur][s * 4096];
      const short* Vsb = &Vs[cur][s * 4096];
      if (kb <= q0A + 31) {
        if (kb + 63 <= q0A)
          ptile2<false>(Ksb, Vsb, qfA, qfB, kb, qrowA, l31, hi,
                        oA0, oA1, oB0, oB1, lA, lB);
        else
          ptile2<true>(Ksb, Vsb, qfA, qfB, kb, qrowA, l31, hi,
                       oA0, oA1, oB0, oB1, lA, lB);
      } else if (kb <= q0B + 31) {
        if (kb + 63 <= q0B)
          ptile<false>(Ksb, Vsb, qfB, kb, qrowB, l31, hi, oB0, oB1, lB);
        else
          ptile<true>(Ksb, Vsb, qfB, kb, qrowB, l31, hi, oB0, oB1, lB);
      }
    }
    __syncthreads();
    cur ^= 1;
  }

  lA += __shfl_xor(lA, 32, 64);
  lB += __shfl_xor(lB, 32, 64);
  {
    const float inv = 1.f / lA;
    const size_t obase = ((size_t)(b * S + qrowA) * H + h) * 64;
    #pragma unroll
    for (int g = 0; g < 4; ++g) {
      s16x4 s0v, s1v;
      #pragma unroll
      for (int i = 0; i < 4; ++i) {
        s0v[i] = f2bf(oA0[4 * g + i] * inv);
        s1v[i] = f2bf(oA1[4 * g + i] * inv);
      }
      *reinterpret_cast<s16x4*>(&O[obase + 8 * g + 4 * hi]) = s0v;
      *reinterpret_cast<s16x4*>(&O[obase + 32 + 8 * g + 4 * hi]) = s1v;
    }
  }
  {
    const float inv = 1.f / lB;
    const size_t obase = ((size_t)(b * S + qrowB) * H + h) * 64;
    #pragma unroll
    for (int g = 0; g < 4; ++g) {
      s16x4 s0v, s1v;
      #pragma unroll
      for (int i = 0; i < 4; ++i) {
        s0v[i] = f2bf(oB0[4 * g + i] * inv);
        s1v[i] = f2bf(oB1[4 * g + i] * inv);
      }
      *reinterpret_cast<s16x4*>(&O[obase + 8 * g + 4 * hi]) = s0v;
      *reinterpret_cast<s16x4*>(&O[obase + 32 + 8 * g + 4 * hi]) = s1v;
    }
  }
}

extern "C" void kernel_launch(void* const* d_in, const int* in_sizes, int n_in,
                              void* d_out, int out_size, void* d_ws, size_t ws_size,
                              hipStream_t stream) {
  const float* x  = (const float*)d_in[0];
  const float* fc = (const float*)d_in[1];
  const float* fs = (const float*)d_in[2];
  // d_in[3] = mask (unused; causality applied analytically)
  const float* wq = (const float*)d_in[4];
  const float* wk = (const float*)d_in[5];
  const float* wv = (const float*)d_in[6];
  const float* wo = (const float*)d_in[7];
  float* out = (float*)d_out;

  // workspace layout; wqT/wkT/wvT are contiguous = fused wqkvT [3072][2048]
  short* xb  = (short*)d_ws;       // [4096][2048]
  short* wqT = xb  + 8388608;      // [2048][2048]
  short* wkT = wqT + 4194304;      // [512][2048]
  short* wvT = wkT + 1048576;      // [512][2048]
  short* woT = wvT + 1048576;      // [2048][2048]
  short* Qb  = woT + 4194304;      // [b,s,32,64] (raw; rope+KSC applied in attn)
  short* Kb  = Qb  + 8388608;      // [b,s,8,64]
  short* VTb = Kb  + 2097152;      // [b*8+kvh][64][2048]
  short* attb = xb;                // alias: x dead after fused QKV GEMM

  // 1) fused prep (vectorized transpose)
  prep_kernel<<<dim3(64, 64, 5), 256, 0, stream>>>(x, wq, wk, wv, wo,
                                                   xb, wqT, wkT, wvT, woT);

  // 2) fused QKV projection: 256x192 tile, grid 16x16 = 256 blocks = full chip
  gemm_qkv<<<dim3(16, 16), 512, 0, stream>>>(xb, wqT, Qb, Kb, VTb);

  // 3) RoPE on K only (Q-rope fused into attn)
  rope_k<<<1024, 256, 0, stream>>>(Kb, fc, fs);

  // 4) attention: KVBLK=256 (9 barriers/block)
  attn3<<<dim3(16, 8, 2), 512, 0, stream>>>(Qb, Kb, VTb, fc, fs, attb);

  // 5) output projection: 128x256 tile, 2-deep (R17 structure), nt C-stores
  gemm_out<<<dim3(32, 8), 512, 0, stream>>>(attb, woT, out, 4096, 2048, 2048);
}

// Round 20
// 209.501 us; speedup vs baseline: 1.0170x; 1.0170x over previous
//
#include <hip/hip_runtime.h>
#include <hip/hip_bf16.h>

typedef __bf16 bf16x8 __attribute__((ext_vector_type(8)));
typedef float f32x4 __attribute__((ext_vector_type(4)));
typedef float f32x16 __attribute__((ext_vector_type(16)));
typedef short s16x4 __attribute__((ext_vector_type(4)));
typedef short s16x8 __attribute__((ext_vector_type(8)));

__device__ __forceinline__ short f2bf(float f) {
  union { __bf16 h; short s; } p; p.h = (__bf16)f; return p.s;
}
__device__ __forceinline__ float bf2f(short s) {
  union { unsigned u; float f; } v; v.u = ((unsigned)(unsigned short)s) << 16;
  return v.f;
}
__device__ __forceinline__ void gload16(const void* g, void* l) {
  __builtin_amdgcn_global_load_lds(
      (const __attribute__((address_space(1))) unsigned*)g,
      (__attribute__((address_space(3))) unsigned*)l, 16, 0, 0);
}
__device__ __forceinline__ unsigned pack2(float lo, float hi) {
  union { __bf16 h[2]; unsigned u; } p;
  p.h[0] = (__bf16)lo; p.h[1] = (__bf16)hi;   // v_cvt_pk_bf16_f32
  return p.u;
}
__device__ __forceinline__ float vsum16(const f32x16& v) {
  const float a0 = v[0] + v[1], a1 = v[2] + v[3], a2 = v[4] + v[5], a3 = v[6] + v[7];
  const float a4 = v[8] + v[9], a5 = v[10] + v[11], a6 = v[12] + v[13], a7 = v[14] + v[15];
  return ((a0 + a1) + (a2 + a3)) + ((a4 + a5) + (a6 + a7));
}

constexpr float KSC = 0.18033688f;  // 1/sqrt(64) * log2(e) — folded into Q-rope in attn

// ---------------- fused prep: x fp32->bf16 (z=4) + 4 weight transposes (z=0..3) ----------------
__global__ __launch_bounds__(256) void prep_kernel(const float* __restrict__ x,
                                                   const float* __restrict__ wq,
                                                   const float* __restrict__ wk,
                                                   const float* __restrict__ wv,
                                                   const float* __restrict__ wo,
                                                   short* __restrict__ xb,
                                                   short* __restrict__ wqT,
                                                   short* __restrict__ wkT,
                                                   short* __restrict__ wvT,
                                                   short* __restrict__ woT) {
  __shared__ float T[32][36];
  const int z = blockIdx.z;
  if (z == 4) {
    const int bid = blockIdx.y * 64 + blockIdx.x;
    const int i0 = bid * 512 + threadIdx.x;
    #pragma unroll
    for (int q = 0; q < 2; ++q) {
      const int i = i0 + q * 256;
      const float4 v = reinterpret_cast<const float4*>(x)[i];
      s16x4 o;
      o[0] = f2bf(v.x); o[1] = f2bf(v.y); o[2] = f2bf(v.z); o[3] = f2bf(v.w);
      reinterpret_cast<s16x4*>(xb)[i] = o;
    }
    return;
  }
  const float* W; short* WT; int N;
  if (z == 0)      { W = wq; WT = wqT; N = 2048; }
  else if (z == 1) { W = wk; WT = wkT; N = 512; }
  else if (z == 2) { W = wv; WT = wvT; N = 512; }
  else             { W = wo; WT = woT; N = 2048; }
  const int k0 = blockIdx.x * 32, n0 = blockIdx.y * 32;
  if (n0 >= N) return;
  const int r = threadIdx.x >> 3;
  const int c4 = (threadIdx.x & 7) * 4;
  {
    const float4 v = *reinterpret_cast<const float4*>(&W[(size_t)(k0 + r) * N + n0 + c4]);
    T[r][c4 + 0] = v.x; T[r][c4 + 1] = v.y; T[r][c4 + 2] = v.z; T[r][c4 + 3] = v.w;
  }
  __syncthreads();
  {
    s16x4 o;
    #pragma unroll
    for (int i = 0; i < 4; ++i) o[i] = f2bf(T[c4 + i][r]);
    *reinterpret_cast<s16x4*>(&WT[(size_t)(n0 + r) * 2048 + k0 + c4]) = o;
  }
}

// ---------------- RoPE on K only (Q-rope fused into attn) ----------------
__global__ void rope_k(short* __restrict__ K, const float* __restrict__ cosT,
                       const float* __restrict__ sinT) {
  const int i = blockIdx.x * blockDim.x + threadIdx.x;
  const int s = (i >> 6) & 2047;
  const int p0 = (i & 7) * 4;
  s16x8 v = *reinterpret_cast<const s16x8*>(&K[(size_t)i * 8]);
  #pragma unroll
  for (int jj = 0; jj < 4; ++jj) {
    const float c = cosT[s * 32 + p0 + jj];
    const float sn = sinT[s * 32 + p0 + jj];
    const float e = bf2f(v[2 * jj]), o = bf2f(v[2 * jj + 1]);
    v[2 * jj] = f2bf(e * c - o * sn);
    v[2 * jj + 1] = f2bf(e * sn + o * c);
  }
  *reinterpret_cast<s16x8*>(&K[(size_t)i * 8]) = v;
}

// ---------------- QKV GEMM (R16-verified, verbatim): 256x192, grid 16x16 ----------------
__global__ __launch_bounds__(512, 2) void gemm_qkv(const short* __restrict__ A,
                                                   const short* __restrict__ BT,
                                                   short* __restrict__ C0,   // Q [4096][2048]
                                                   short* __restrict__ C1,   // K [4096][512]
                                                   short* __restrict__ C2) { // VT [16][64][2048]
  constexpr int BM = 256, BN = 192, BK = 64, K = 2048, NT = K / BK;
  __shared__ short As[2][BM * BK];
  __shared__ short Bs[2][BN * BK];
  const int tid = threadIdx.x, lane = tid & 63, wid = tid >> 6;
  const int wm = wid >> 1, wn = wid & 1;
  const int lr = lane & 15, hi2 = lane >> 4;

  int bid = blockIdx.y * 16 + blockIdx.x;
  bid = (bid & 7) * 32 + (bid >> 3);          // XCD swizzle (256 % 8 == 0, bijective)
  const int row0 = (bid & 15) * BM;
  const int col0 = (bid >> 4) * BN;

  size_t aSrc[4]; int aDst[4];
  size_t bSrc[3]; int bDst[3];
  #pragma unroll
  for (int i = 0; i < 4; ++i) {
    const int c = i * 512 + tid, r = c >> 3, ch = c & 7;
    aSrc[i] = (size_t)(row0 + r) * K + (ch ^ (r & 7)) * 8;
    aDst[i] = c * 8;
  }
  #pragma unroll
  for (int i = 0; i < 3; ++i) {
    const int c = i * 512 + tid, r = c >> 3, ch = c & 7;
    bSrc[i] = (size_t)(col0 + r) * K + (ch ^ (r & 7)) * 8;
    bDst[i] = c * 8;
  }

  f32x4 acc[4][6] = {};

  #pragma unroll
  for (int i = 0; i < 4; ++i) gload16(&A[aSrc[i]], &As[0][aDst[i]]);
  #pragma unroll
  for (int i = 0; i < 3; ++i) gload16(&BT[bSrc[i]], &Bs[0][bDst[i]]);

  int buf = 0;
  for (int t = 0; t < NT; ++t) {
    __syncthreads();
    if (t + 1 < NT) {
      const int k1 = (t + 1) * BK;
      #pragma unroll
      for (int i = 0; i < 4; ++i) gload16(&A[aSrc[i] + k1], &As[buf ^ 1][aDst[i]]);
      #pragma unroll
      for (int i = 0; i < 3; ++i) gload16(&BT[bSrc[i] + k1], &Bs[buf ^ 1][bDst[i]]);
    }
    #pragma unroll
    for (int ks = 0; ks < 2; ++ks) {
      const int sw = ((ks * 4 + hi2) ^ (lr & 7)) * 8;
      bf16x8 af[4], bfr[6];
      #pragma unroll
      for (int m = 0; m < 4; ++m)
        af[m] = *reinterpret_cast<const bf16x8*>(
            &As[buf][(wm * 64 + m * 16 + lr) * BK + sw]);
      #pragma unroll
      for (int n = 0; n < 6; ++n)
        bfr[n] = *reinterpret_cast<const bf16x8*>(
            &Bs[buf][(wn * 96 + n * 16 + lr) * BK + sw]);
      __builtin_amdgcn_s_setprio(1);
      #pragma unroll
      for (int m = 0; m < 4; ++m)
        #pragma unroll
        for (int n = 0; n < 6; ++n)
          acc[m][n] = __builtin_amdgcn_mfma_f32_16x16x32_bf16(af[m], bfr[n], acc[m][n], 0, 0, 0);
      __builtin_amdgcn_s_setprio(0);
    }
    buf ^= 1;
  }

  const int lc = lane & 15, lr4 = (lane >> 4) * 4;
  #pragma unroll
  for (int m = 0; m < 4; ++m) {
    #pragma unroll
    for (int n = 0; n < 6; ++n) {
      const int row = row0 + wm * 64 + m * 16 + lr4;
      const int col = col0 + wn * 96 + n * 16 + lc;
      if (col < 2048) {
        #pragma unroll
        for (int i = 0; i < 4; ++i)
          C0[(size_t)(row + i) * 2048 + col] = f2bf(acc[m][n][i]);
      } else if (col < 2560) {
        #pragma unroll
        for (int i = 0; i < 4; ++i)
          C1[(size_t)(row + i) * 512 + (col - 2048)] = f2bf(acc[m][n][i]);
      } else {
        const int c2 = col - 2560;
        const int kvh = c2 >> 6, d = c2 & 63;
        const int bb = row >> 11, st = row & 2047;
        s16x4 o4;
        #pragma unroll
        for (int i = 0; i < 4; ++i) o4[i] = f2bf(acc[m][n][i]);
        *reinterpret_cast<s16x4*>(&C2[((size_t)(bb * 8 + kvh) * 64 + d) * 2048 + st]) = o4;
      }
    }
  }
}

// ---------------- out-projection GEMM (R17-verified 128x256, verbatim) ----------------
template <int BM, int EPI>
__global__ __launch_bounds__(512, 2) void gemm256(const short* __restrict__ A,
                                                  const short* __restrict__ BT,
                                                  void* __restrict__ C0,
                                                  int M, int N, int K) {
  constexpr int BN = 256, BK = 64;
  constexpr int AIT = (BM * 8) / 512;
  constexpr int MREP = BM / 32;
  __shared__ short As[2][BM * BK];
  __shared__ short Bs[2][BN * BK];
  const int tid = threadIdx.x, lane = tid & 63, wid = tid >> 6;
  const int wm = wid >> 2, wn = wid & 3;
  const int lr = lane & 15, hi2 = lane >> 4;

  const int nwg = gridDim.x * gridDim.y;
  int bid = blockIdx.y * gridDim.x + blockIdx.x;
  bid = (bid & 7) * (nwg >> 3) + (bid >> 3);
  const int row0 = (bid % gridDim.x) * BM;
  const int col0 = (bid / gridDim.x) * BN;

  size_t aSrc[AIT]; int aDst[AIT];
  size_t bSrc[4];   int bDst[4];
  #pragma unroll
  for (int i = 0; i < AIT; ++i) {
    const int c = i * 512 + tid, r = c >> 3, ch = c & 7;
    aSrc[i] = (size_t)(row0 + r) * K + (ch ^ (r & 7)) * 8;
    aDst[i] = c * 8;
  }
  #pragma unroll
  for (int i = 0; i < 4; ++i) {
    const int c = i * 512 + tid, r = c >> 3, ch = c & 7;
    bSrc[i] = (size_t)(col0 + r) * K + (ch ^ (r & 7)) * 8;
    bDst[i] = c * 8;
  }

  f32x4 acc[MREP][4] = {};

  const int NT = K / BK;
  #pragma unroll
  for (int i = 0; i < AIT; ++i) gload16(&A[aSrc[i]], &As[0][aDst[i]]);
  #pragma unroll
  for (int i = 0; i < 4; ++i) gload16(&BT[bSrc[i]], &Bs[0][bDst[i]]);

  int buf = 0;
  for (int t = 0; t < NT; ++t) {
    __syncthreads();
    if (t + 1 < NT) {
      const int k1 = (t + 1) * BK;
      #pragma unroll
      for (int i = 0; i < AIT; ++i) gload16(&A[aSrc[i] + k1], &As[buf ^ 1][aDst[i]]);
      #pragma unroll
      for (int i = 0; i < 4; ++i) gload16(&BT[bSrc[i] + k1], &Bs[buf ^ 1][bDst[i]]);
    }
    #pragma unroll
    for (int ks = 0; ks < 2; ++ks) {
      const int sw = ((ks * 4 + hi2) ^ (lr & 7)) * 8;
      bf16x8 af[MREP], bfr[4];
      #pragma unroll
      for (int m = 0; m < MREP; ++m)
        af[m] = *reinterpret_cast<const bf16x8*>(
            &As[buf][(wm * (BM / 2) + m * 16 + lr) * BK + sw]);
      #pragma unroll
      for (int n = 0; n < 4; ++n)
        bfr[n] = *reinterpret_cast<const bf16x8*>(
            &Bs[buf][(wn * 64 + n * 16 + lr) * BK + sw]);
      __builtin_amdgcn_s_setprio(1);
      #pragma unroll
      for (int m = 0; m < MREP; ++m)
        #pragma unroll
        for (int n = 0; n < 4; ++n)
          acc[m][n] = __builtin_amdgcn_mfma_f32_16x16x32_bf16(af[m], bfr[n], acc[m][n], 0, 0, 0);
      __builtin_amdgcn_s_setprio(0);
    }
    buf ^= 1;
  }

  const int lc = lane & 15, lr4 = (lane >> 4) * 4;
  #pragma unroll
  for (int m = 0; m < MREP; ++m)
    #pragma unroll
    for (int n = 0; n < 4; ++n)
      #pragma unroll
      for (int i = 0; i < 4; ++i) {
        const int row = row0 + wm * (BM / 2) + m * 16 + lr4 + i;
        const int col = col0 + wn * 64 + n * 16 + lc;
        ((float*)C0)[(size_t)row * N + col] = acc[m][n][i];
      }
}

// ---------------- causal GQA flash attention (R17-verified, verbatim) ----------------
__device__ __forceinline__ void rope_qfrag(bf16x8 qf[4], const float* __restrict__ cosT,
                                           const float* __restrict__ sinT, int qrow, int hi) {
  #pragma unroll
  for (int ds = 0; ds < 4; ++ds) {
    const int p0 = ds * 8 + hi * 4;
    const float4 cv = *reinterpret_cast<const float4*>(&cosT[qrow * 32 + p0]);
    const float4 sv = *reinterpret_cast<const float4*>(&sinT[qrow * 32 + p0]);
    const float ca[4] = {cv.x, cv.y, cv.z, cv.w};
    const float sa[4] = {sv.x, sv.y, sv.z, sv.w};
    union { bf16x8 v; s16x8 s; } u; u.v = qf[ds];
    s16x8 r;
    #pragma unroll
    for (int jj = 0; jj < 4; ++jj) {
      const float c = ca[jj] * KSC;
      const float sn = sa[jj] * KSC;
      const float e = bf2f(u.s[2 * jj]), o = bf2f(u.s[2 * jj + 1]);
      r[2 * jj] = f2bf(e * c - o * sn);
      r[2 * jj + 1] = f2bf(e * sn + o * c);
    }
    union { s16x8 s; bf16x8 v; } w; w.s = r;
    qf[ds] = w.v;
  }
}

template <bool MASKED>
__device__ __forceinline__ void ptile(const short* __restrict__ Ksb,
                                      const short* __restrict__ Vsb,
                                      const bf16x8 qf[4], int kb, int qrow,
                                      int l31, int hi,
                                      f32x16& o0, f32x16& o1, float& l_r) {
  f32x16 sa0 = {}, sa1 = {};
  __builtin_amdgcn_s_setprio(1);
  #pragma unroll
  for (int ds = 0; ds < 4; ++ds) {
    const int c0 = ((ds * 2 + hi) ^ (l31 & 7)) * 8;
    const bf16x8 kf0 = *reinterpret_cast<const bf16x8*>(&Ksb[l31 * 64 + c0]);
    const bf16x8 kf1 = *reinterpret_cast<const bf16x8*>(&Ksb[(32 + l31) * 64 + c0]);
    sa0 = __builtin_amdgcn_mfma_f32_32x32x16_bf16(kf0, qf[ds], sa0, 0, 0, 0);
    sa1 = __builtin_amdgcn_mfma_f32_32x32x16_bf16(kf1, qf[ds], sa1, 0, 0, 0);
  }
  __builtin_amdgcn_s_setprio(0);
  if (MASKED) {
    #pragma unroll
    for (int r = 0; r < 16; ++r) {
      const int kk = kb + (r & 3) + 8 * (r >> 2) + 4 * hi;
      if (kk > qrow) sa0[r] = -1e30f;
      if (kk + 32 > qrow) sa1[r] = -1e30f;
    }
  }
  #pragma unroll
  for (int r = 0; r < 16; ++r) {
    sa0[r] = exp2f(sa0[r]);
    sa1[r] = exp2f(sa1[r]);
  }
  l_r += vsum16(sa0) + vsum16(sa1);
  bf16x8 paf[4];
  #pragma unroll
  for (int ks = 0; ks < 4; ++ks) {
    union { unsigned w[4]; bf16x8 v; } u;
    #pragma unroll
    for (int w2 = 0; w2 < 4; ++w2) {
      const int rbase = (ks & 1) * 8 + w2 * 2;
      if (ks < 2) u.w[w2] = pack2(sa0[rbase], sa0[rbase + 1]);
      else        u.w[w2] = pack2(sa1[rbase], sa1[rbase + 1]);
    }
    paf[ks] = u.v;
  }
  __builtin_amdgcn_s_setprio(1);
  #pragma unroll
  for (int ks = 0; ks < 4; ++ks) {
    const int g0 = ((2 * ks) ^ (l31 & 7)) * 8 + hi * 4;
    const int g1 = ((2 * ks + 1) ^ (l31 & 7)) * 8 + hi * 4;
    union { s16x4 h2[2]; bf16x8 v; } a0, a1;
    a0.h2[0] = *reinterpret_cast<const s16x4*>(&Vsb[l31 * 64 + g0]);
    a0.h2[1] = *reinterpret_cast<const s16x4*>(&Vsb[l31 * 64 + g1]);
    a1.h2[0] = *reinterpret_cast<const s16x4*>(&Vsb[(32 + l31) * 64 + g0]);
    a1.h2[1] = *reinterpret_cast<const s16x4*>(&Vsb[(32 + l31) * 64 + g1]);
    o0 = __builtin_amdgcn_mfma_f32_32x32x16_bf16(a0.v, paf[ks], o0, 0, 0, 0);
    o1 = __builtin_amdgcn_mfma_f32_32x32x16_bf16(a1.v, paf[ks], o1, 0, 0, 0);
  }
  __builtin_amdgcn_s_setprio(0);
}

template <bool MA>
__device__ __forceinline__ void ptile2(const short* __restrict__ Ksb,
                                       const short* __restrict__ Vsb,
                                       const bf16x8 qfA[4], const bf16x8 qfB[4],
                                       int kb, int qrowA, int l31, int hi,
                                       f32x16& oA0, f32x16& oA1, f32x16& oB0, f32x16& oB1,
                                       float& lA, float& lB) {
  f32x16 a0 = {}, a1 = {}, b0 = {}, b1 = {};
  __builtin_amdgcn_s_setprio(1);
  #pragma unroll
  for (int ds = 0; ds < 4; ++ds) {
    const int c0 = ((ds * 2 + hi) ^ (l31 & 7)) * 8;
    const bf16x8 kf0 = *reinterpret_cast<const bf16x8*>(&Ksb[l31 * 64 + c0]);
    const bf16x8 kf1 = *reinterpret_cast<const bf16x8*>(&Ksb[(32 + l31) * 64 + c0]);
    a0 = __builtin_amdgcn_mfma_f32_32x32x16_bf16(kf0, qfA[ds], a0, 0, 0, 0);
    b0 = __builtin_amdgcn_mfma_f32_32x32x16_bf16(kf0, qfB[ds], b0, 0, 0, 0);
    a1 = __builtin_amdgcn_mfma_f32_32x32x16_bf16(kf1, qfA[ds], a1, 0, 0, 0);
    b1 = __builtin_amdgcn_mfma_f32_32x32x16_bf16(kf1, qfB[ds], b1, 0, 0, 0);
  }
  __builtin_amdgcn_s_setprio(0);
  if (MA) {
    #pragma unroll
    for (int r = 0; r < 16; ++r) {
      const int kk = kb + (r & 3) + 8 * (r >> 2) + 4 * hi;
      if (kk > qrowA) a0[r] = -1e30f;
      if (kk + 32 > qrowA) a1[r] = -1e30f;
    }
  }
  #pragma unroll
  for (int r = 0; r < 16; ++r) {
    a0[r] = exp2f(a0[r]);
    b0[r] = exp2f(b0[r]);
    a1[r] = exp2f(a1[r]);
    b1[r] = exp2f(b1[r]);
  }
  lA += vsum16(a0) + vsum16(a1);
  lB += vsum16(b0) + vsum16(b1);
  bf16x8 pafA[4], pafB[4];
  #pragma unroll
  for (int ks = 0; ks < 4; ++ks) {
    union { unsigned w[4]; bf16x8 v; } ua, ub;
    #pragma unroll
    for (int w2 = 0; w2 < 4; ++w2) {
      const int rbase = (ks & 1) * 8 + w2 * 2;
      if (ks < 2) { ua.w[w2] = pack2(a0[rbase], a0[rbase + 1]);
                    ub.w[w2] = pack2(b0[rbase], b0[rbase + 1]); }
      else        { ua.w[w2] = pack2(a1[rbase], a1[rbase + 1]);
                    ub.w[w2] = pack2(b1[rbase], b1[rbase + 1]); }
    }
    pafA[ks] = ua.v; pafB[ks] = ub.v;
  }
  __builtin_amdgcn_s_setprio(1);
  #pragma unroll
  for (int ks = 0; ks < 4; ++ks) {
    const int g0 = ((2 * ks) ^ (l31 & 7)) * 8 + hi * 4;
    const int g1 = ((2 * ks + 1) ^ (l31 & 7)) * 8 + hi * 4;
    union { s16x4 h2[2]; bf16x8 v; } v0, v1;
    v0.h2[0] = *reinterpret_cast<const s16x4*>(&Vsb[l31 * 64 + g0]);
    v0.h2[1] = *reinterpret_cast<const s16x4*>(&Vsb[l31 * 64 + g1]);
    v1.h2[0] = *reinterpret_cast<const s16x4*>(&Vsb[(32 + l31) * 64 + g0]);
    v1.h2[1] = *reinterpret_cast<const s16x4*>(&Vsb[(32 + l31) * 64 + g1]);
    oA0 = __builtin_amdgcn_mfma_f32_32x32x16_bf16(v0.v, pafA[ks], oA0, 0, 0, 0);
    oB0 = __builtin_amdgcn_mfma_f32_32x32x16_bf16(v0.v, pafB[ks], oB0, 0, 0, 0);
    oA1 = __builtin_amdgcn_mfma_f32_32x32x16_bf16(v1.v, pafA[ks], oA1, 0, 0, 0);
    oB1 = __builtin_amdgcn_mfma_f32_32x32x16_bf16(v1.v, pafB[ks], oB1, 0, 0, 0);
  }
  __builtin_amdgcn_s_setprio(0);
}

__global__ __launch_bounds__(512, 2) void attn3(const short* __restrict__ Q,
                                                const short* __restrict__ K,
                                                const short* __restrict__ VT,
                                                const float* __restrict__ cosT,
                                                const float* __restrict__ sinT,
                                                short* __restrict__ O) {
  constexpr int S = 2048, H = 32;
  const int pair = blockIdx.x, kvh = blockIdx.y, b = blockIdx.z;
  const int tid = threadIdx.x, lane = tid & 63, wid = tid >> 6;
  const int hg = wid & 3, rowhalf = wid >> 2;
  const int h = kvh * 4 + hg;
  const int l31 = lane & 31, hi = lane >> 5;
  const int qpA = pair, qpB = 31 - pair;
  const int q0A = qpA * 64 + rowhalf * 32, q0B = qpB * 64 + rowhalf * 32;
  const int qrowA = q0A + l31, qrowB = q0B + l31;
  const int bk = b * 8 + kvh;

  __shared__ short Ks[2][16384];
  __shared__ short Vs[2][16384];

  bf16x8 qfA[4], qfB[4];
  {
    const size_t qa = ((size_t)(b * S + qrowA) * H + h) * 64;
    const size_t qb = ((size_t)(b * S + qrowB) * H + h) * 64;
    #pragma unroll
    for (int ds = 0; ds < 4; ++ds) {
      qfA[ds] = *reinterpret_cast<const bf16x8*>(&Q[qa + ds * 16 + hi * 8]);
      qfB[ds] = *reinterpret_cast<const bf16x8*>(&Q[qb + ds * 16 + hi * 8]);
    }
    rope_qfrag(qfA, cosT, sinT, qrowA, hi);
    rope_qfrag(qfB, cosT, sinT, qrowB, hi);
  }

  f32x16 oA0 = {}, oA1 = {}, oB0 = {}, oB1 = {};
  float lA = 0.f, lB = 0.f;

  const int njt = (qpB + 4) >> 2;
  const size_t kroot = ((size_t)b * S * 8 + kvh) * 64;
  const size_t vroot = (size_t)bk * 64 * S;

  const int sr = tid >> 3, sch = tid & 7;
  const int cs8 = (sch ^ (sr & 7)) * 8;

  auto stage = [&](int j, int bufi) {
    #pragma unroll
    for (int s = 0; s < 4; ++s) {
      gload16(&K[kroot + (size_t)(j * 256 + s * 64 + sr) * 512 + cs8],
              &Ks[bufi][s * 4096 + tid * 8]);
      gload16(&VT[vroot + (size_t)sr * S + j * 256 + s * 64 + cs8],
              &Vs[bufi][s * 4096 + tid * 8]);
    }
  };

  stage(0, 0);
  __syncthreads();

  int cur = 0;
  for (int j = 0; j < njt; ++j) {
    if (j + 1 < njt) stage(j + 1, cur ^ 1);
    #pragma unroll
    for (int s = 0; s < 4; ++s) {
      const int kb = j * 256 + s * 64;
      const short* Ksb = &Ks[cur][s * 4096];
      const short* Vsb = &Vs[cur][s * 4096];
      if (kb <= q0A + 31) {
        if (kb + 63 <= q0A)
          ptile2<false>(Ksb, Vsb, qfA, qfB, kb, qrowA, l31, hi,
                        oA0, oA1, oB0, oB1, lA, lB);
        else
          ptile2<true>(Ksb, Vsb, qfA, qfB, kb, qrowA, l31, hi,
                       oA0, oA1, oB0, oB1, lA, lB);
      } else if (kb <= q0B + 31) {
        if (kb + 63 <= q0B)
          ptile<false>(Ksb, Vsb, qfB, kb, qrowB, l31, hi, oB0, oB1, lB);
        else
          ptile<true>(Ksb, Vsb, qfB, kb, qrowB, l31, hi, oB0, oB1, lB);
      }
    }
    __syncthreads();
    cur ^= 1;
  }

  lA += __shfl_xor(lA, 32, 64);
  lB += __shfl_xor(lB, 32, 64);
  {
    const float inv = 1.f / lA;
    const size_t obase = ((size_t)(b * S + qrowA) * H + h) * 64;
    #pragma unroll
    for (int g = 0; g < 4; ++g) {
      s16x4 s0v, s1v;
      #pragma unroll
      for (int i = 0; i < 4; ++i) {
        s0v[i] = f2bf(oA0[4 * g + i] * inv);
        s1v[i] = f2bf(oA1[4 * g + i] * inv);
      }
      *reinterpret_cast<s16x4*>(&O[obase + 8 * g + 4 * hi]) = s0v;
      *reinterpret_cast<s16x4*>(&O[obase + 32 + 8 * g + 4 * hi]) = s1v;
    }
  }
  {
    const float inv = 1.f / lB;
    const size_t obase = ((size_t)(b * S + qrowB) * H + h) * 64;
    #pragma unroll
    for (int g = 0; g < 4; ++g) {
      s16x4 s0v, s1v;
      #pragma unroll
      for (int i = 0; i < 4; ++i) {
        s0v[i] = f2bf(oB0[4 * g + i] * inv);
        s1v[i] = f2bf(oB1[4 * g + i] * inv);
      }
      *reinterpret_cast<s16x4*>(&O[obase + 8 * g + 4 * hi]) = s0v;
      *reinterpret_cast<s16x4*>(&O[obase + 32 + 8 * g + 4 * hi]) = s1v;
    }
  }
}

extern "C" void kernel_launch(void* const* d_in, const int* in_sizes, int n_in,
                              void* d_out, int out_size, void* d_ws, size_t ws_size,
                              hipStream_t stream) {
  const float* x  = (const float*)d_in[0];
  const float* fc = (const float*)d_in[1];
  const float* fs = (const float*)d_in[2];
  // d_in[3] = mask (unused; causality applied analytically)
  const float* wq = (const float*)d_in[4];
  const float* wk = (const float*)d_in[5];
  const float* wv = (const float*)d_in[6];
  const float* wo = (const float*)d_in[7];
  float* out = (float*)d_out;

  // workspace layout; wqT/wkT/wvT are contiguous = fused wqkvT [3072][2048]
  short* xb  = (short*)d_ws;       // [4096][2048]
  short* wqT = xb  + 8388608;      // [2048][2048]
  short* wkT = wqT + 4194304;      // [512][2048]
  short* wvT = wkT + 1048576;      // [512][2048]
  short* woT = wvT + 1048576;      // [2048][2048]
  short* Qb  = woT + 4194304;      // [b,s,32,64] (raw; rope+KSC applied in attn)
  short* Kb  = Qb  + 8388608;      // [b,s,8,64]
  short* VTb = Kb  + 2097152;      // [b*8+kvh][64][2048]
  short* attb = xb;                // alias: x dead after fused QKV GEMM

  // 1) fused prep (vectorized transpose)
  prep_kernel<<<dim3(64, 64, 5), 256, 0, stream>>>(x, wq, wk, wv, wo,
                                                   xb, wqT, wkT, wvT, woT);

  // 2) fused QKV projection: 256x192 tile, grid 16x16 = 256 blocks = full chip
  gemm_qkv<<<dim3(16, 16), 512, 0, stream>>>(xb, wqT, Qb, Kb, VTb);

  // 3) RoPE on K only (Q-rope fused into attn)
  rope_k<<<1024, 256, 0, stream>>>(Kb, fc, fs);

  // 4) attention: KVBLK=256 (9 barriers/block)
  attn3<<<dim3(16, 8, 2), 512, 0, stream>>>(Qb, Kb, VTb, fc, fs, attb);

  // 5) output projection: 128x256 tile, grid 32x8 = 256 blocks (1/CU)
  gemm256<128, 1><<<dim3(32, 8), 512, 0, stream>>>(attb, woT, out, 4096, 2048, 2048);
}